// Round 2
// baseline (333.824 us; speedup 1.0000x reference)
//
#include <hip/hip_runtime.h>
#include <hip/hip_bf16.h>
#include <stdint.h>

typedef short short8 __attribute__((ext_vector_type(8)));
typedef float f32x4 __attribute__((ext_vector_type(4)));
typedef unsigned short ushort_t;

__device__ __forceinline__ unsigned short f2b(float x) {
  __hip_bfloat16 h = __float2bfloat16(x);
  return *reinterpret_cast<unsigned short*>(&h);
}

// ---------------- X f32 -> bf16 (same layout) ----------------
__global__ void cvt_kernel(const float* __restrict__ in, unsigned short* __restrict__ out, int n4) {
  int i = blockIdx.x * blockDim.x + threadIdx.x;
  if (i >= n4) return;
  const float4 v = reinterpret_cast<const float4*>(in)[i];
  ushort4 o;
  o.x = f2b(v.x); o.y = f2b(v.y); o.z = f2b(v.z); o.w = f2b(v.w);
  reinterpret_cast<ushort4*>(out)[i] = o;
}

// ---------------- W[K][N] f32 -> Wt[N][K] bf16 (transpose + convert) ----------------
__global__ void tpose_kernel(const float* __restrict__ W, unsigned short* __restrict__ Wt,
                             int K, int N) {
  __shared__ float tile[32][33];
  const int nkb = K >> 5;
  const int bk = blockIdx.x % nkb, bn = blockIdx.x / nkb;
  const int k0 = bk * 32, n0 = bn * 32;
  const int tx = threadIdx.x & 31, ty = threadIdx.x >> 5;  // ty 0..7
#pragma unroll
  for (int i = 0; i < 4; i++) {
    int r = ty + i * 8;
    tile[r][tx] = W[(size_t)(k0 + r) * N + n0 + tx];
  }
  __syncthreads();
#pragma unroll
  for (int i = 0; i < 4; i++) {
    int r = ty + i * 8;
    Wt[(size_t)(n0 + r) * K + k0 + tx] = f2b(tile[tx][r]);
  }
}

// ---------------- GEMM: C[M][N] = A[M][K](bf16) * Bt[N][K]^T(bf16) + bias ----------------
// MODE 0: QKV epilogue -> scatter bf16 into Q/K/V [3][B*H][S][64]
// MODE 1: proj epilogue -> f32 out [M][N]
template<int MODE>
__global__ __launch_bounds__(256)
void gemm_bt(const unsigned short* __restrict__ A, const unsigned short* __restrict__ Bt,
             const float* __restrict__ bias, void* __restrict__ out, int N) {
  constexpr int K = 1024;
  __shared__ __align__(16) unsigned short As[128 * 32];
  __shared__ __align__(16) unsigned short Bs[128 * 32];
  const int nbn = N >> 7;
  const int bm = blockIdx.x / nbn, bn = blockIdx.x % nbn;
  const int tid = threadIdx.x;
  const int lane = tid & 63, wave = tid >> 6;
  const int lo = lane & 15, g = lane >> 4;
  const int wr = (wave >> 1) * 64, wc = (wave & 1) * 64;

  const size_t arow0 = (size_t)bm * 128;
  const size_t brow0 = (size_t)bn * 128;

  f32x4 acc[4][4] = {};

  const int r_a = tid >> 2;       // row within 64-row stage chunk
  const int c8  = (tid & 3) * 8;  // k element offset

  for (int kb = 0; kb < K; kb += 32) {
    uint4 va0 = *reinterpret_cast<const uint4*>(A + (arow0 + r_a) * K + kb + c8);
    uint4 va1 = *reinterpret_cast<const uint4*>(A + (arow0 + 64 + r_a) * K + kb + c8);
    uint4 vb0 = *reinterpret_cast<const uint4*>(Bt + (brow0 + r_a) * K + kb + c8);
    uint4 vb1 = *reinterpret_cast<const uint4*>(Bt + (brow0 + 64 + r_a) * K + kb + c8);
    __syncthreads();  // previous tile fully consumed
    *reinterpret_cast<uint4*>(As + (size_t)tid * 8) = va0;
    *reinterpret_cast<uint4*>(As + 2048 + (size_t)tid * 8) = va1;
    *reinterpret_cast<uint4*>(Bs + (size_t)tid * 8) = vb0;
    *reinterpret_cast<uint4*>(Bs + 2048 + (size_t)tid * 8) = vb1;
    __syncthreads();
    short8 af[4], bf[4];
#pragma unroll
    for (int m = 0; m < 4; m++)
      af[m] = *reinterpret_cast<const short8*>(As + (wr + m * 16 + lo) * 32 + g * 8);
#pragma unroll
    for (int n = 0; n < 4; n++)
      bf[n] = *reinterpret_cast<const short8*>(Bs + (wc + n * 16 + lo) * 32 + g * 8);
#pragma unroll
    for (int m = 0; m < 4; m++)
#pragma unroll
      for (int n = 0; n < 4; n++)
        acc[m][n] = __builtin_amdgcn_mfma_f32_16x16x32_bf16(af[m], bf[n], acc[m][n], 0, 0, 0);
  }

#pragma unroll
  for (int m = 0; m < 4; m++) {
#pragma unroll
    for (int n = 0; n < 4; n++) {
      const int col = (int)brow0 + wc + n * 16 + lo;
      const float bv = bias[col];
#pragma unroll
      for (int r = 0; r < 4; r++) {
        const int row = (int)arow0 + wr + m * 16 + g * 4 + r;
        const float v = acc[m][n][r] + bv;
        if (MODE == 0) {
          unsigned short* dst = reinterpret_cast<unsigned short*>(out);
          const int which = col >> 10, rem = col & 1023;
          const int h = rem >> 6, d = rem & 63;
          const int b = row >> 11, s = row & 2047;
          const size_t idx = ((size_t)which * 32 + (size_t)(b * 16 + h)) * 2048 * 64 +
                             (size_t)s * 64 + d;
          dst[idx] = f2b(v);
        } else {
          reinterpret_cast<float*>(out)[(size_t)row * N + col] = v;
        }
      }
    }
  }
}

// ---------------- causal flash attention, one wave per 16 q-rows ----------------
// Q/K/V: [B*H][S][64] bf16.  Out Ab: [B][S][H*64] bf16 (merged heads).
__global__ __launch_bounds__(256)
void attn_kernel(const unsigned short* __restrict__ Qb, const unsigned short* __restrict__ Kb,
                 const unsigned short* __restrict__ Vb, unsigned short* __restrict__ Ab) {
  constexpr int S = 2048, HD = 64;
  const int tid = threadIdx.x;
  const int lane = tid & 63, wave = tid >> 6;
  const int lo = lane & 15, g = lane >> 4;
  const int bh = blockIdx.x >> 5;
  const int qblk = blockIdx.x & 31;
  const int qbase = qblk * 64 + wave * 16;
  const unsigned short* Qh = Qb + (size_t)bh * S * HD;
  const unsigned short* Kh = Kb + (size_t)bh * S * HD;
  const unsigned short* Vh = Vb + (size_t)bh * S * HD;

  // Q fragments (B operand of swapped QK^T): lane holds Q[qbase+lo][d], d in g*8..g*8+7 (+32)
  const short8 qf0 = *reinterpret_cast<const short8*>(Qh + (size_t)(qbase + lo) * HD + g * 8);
  const short8 qf1 = *reinterpret_cast<const short8*>(Qh + (size_t)(qbase + lo) * HD + 32 + g * 8);

  float m = -1e30f, lsum = 0.f;
  f32x4 o[4] = {};
  const int q_lane = qbase + lo;
  const int nchunk = (qbase + 16 + 31) >> 5;

  for (int c = 0; c < nchunk; c++) {
    const int kk0 = c * 32;
    // S^T tiles: rows kk (4g+r), cols q (lo)
    f32x4 st[2];
#pragma unroll
    for (int t = 0; t < 2; t++) {
      const unsigned short* kp = Kh + (size_t)(kk0 + t * 16 + lo) * HD + g * 8;
      const short8 kf0 = *reinterpret_cast<const short8*>(kp);
      const short8 kf1 = *reinterpret_cast<const short8*>(kp + 32);
      f32x4 z = {0.f, 0.f, 0.f, 0.f};
      z = __builtin_amdgcn_mfma_f32_16x16x32_bf16(kf0, qf0, z, 0, 0, 0);
      z = __builtin_amdgcn_mfma_f32_16x16x32_bf16(kf1, qf1, z, 0, 0, 0);
      st[t] = z;
    }
    float s[8];
#pragma unroll
    for (int j = 0; j < 8; j++) {
      const int kk = kk0 + ((j >> 2) << 4) + g * 4 + (j & 3);
      const float v = st[j >> 2][j & 3] * 0.125f;
      s[j] = (kk > q_lane) ? -10000.f : v;
    }
    float tmax = s[0];
#pragma unroll
    for (int j = 1; j < 8; j++) tmax = fmaxf(tmax, s[j]);
    tmax = fmaxf(tmax, __shfl_xor(tmax, 16));
    tmax = fmaxf(tmax, __shfl_xor(tmax, 32));
    const float mn = fmaxf(m, tmax);
    const float cf = __expf(m - mn);
    m = mn;
    float ps = 0.f;
    short8 pf;
#pragma unroll
    for (int j = 0; j < 8; j++) {
      const float p = __expf(s[j] - mn);
      ps += p;
      pf[j] = (short)f2b(p);
    }
    lsum = lsum * cf + ps;
    // rescale O (rows are q' = 4g+r; cf lives at lane q')
#pragma unroll
    for (int r = 0; r < 4; r++) {
      const float cr = __shfl(cf, g * 4 + r);
      o[0][r] *= cr; o[1][r] *= cr; o[2][r] *= cr; o[3][r] *= cr;
    }
    // V fragments: element j holds V[kk0 + (j>>2)*16 + 4g + (j&3)][t*16 + lo]
    short8 vf0, vf1, vf2, vf3;
#pragma unroll
    for (int j = 0; j < 8; j++) {
      const int row = kk0 + ((j >> 2) << 4) + g * 4 + (j & 3);
      const unsigned short* vp = Vh + (size_t)row * HD + lo;
      vf0[j] = (short)vp[0];
      vf1[j] = (short)vp[16];
      vf2[j] = (short)vp[32];
      vf3[j] = (short)vp[48];
    }
    o[0] = __builtin_amdgcn_mfma_f32_16x16x32_bf16(pf, vf0, o[0], 0, 0, 0);
    o[1] = __builtin_amdgcn_mfma_f32_16x16x32_bf16(pf, vf1, o[1], 0, 0, 0);
    o[2] = __builtin_amdgcn_mfma_f32_16x16x32_bf16(pf, vf2, o[2], 0, 0, 0);
    o[3] = __builtin_amdgcn_mfma_f32_16x16x32_bf16(pf, vf3, o[3], 0, 0, 0);
  }

  lsum += __shfl_xor(lsum, 16);
  lsum += __shfl_xor(lsum, 32);

  const int b = bh >> 4, h = bh & 15;
#pragma unroll
  for (int r = 0; r < 4; r++) {
    const float li = 1.f / __shfl(lsum, g * 4 + r);
    const int srow = qbase + g * 4 + r;
    unsigned short* dst = Ab + ((size_t)b * S + srow) * 1024 + h * 64 + lo;
    dst[0]  = f2b(o[0][r] * li);
    dst[16] = f2b(o[1][r] * li);
    dst[32] = f2b(o[2][r] * li);
    dst[48] = f2b(o[3][r] * li);
  }
}

extern "C" void kernel_launch(void* const* d_in, const int* in_sizes, int n_in,
                              void* d_out, int out_size, void* d_ws, size_t ws_size,
                              hipStream_t stream) {
  const float* hs        = (const float*)d_in[0];  // [2,2048,1024]
  const float* c_attn_w  = (const float*)d_in[1];  // [1024,3072]
  const float* c_attn_b  = (const float*)d_in[2];  // [3072]
  const float* c_proj_w  = (const float*)d_in[3];  // [1024,1024]
  const float* c_proj_b  = (const float*)d_in[4];  // [1024]

  char* ws = (char*)d_ws;
  unsigned short* Xb    = (unsigned short*)ws;  ws += (size_t)4096 * 1024 * 2;
  unsigned short* Wqkvt = (unsigned short*)ws;  ws += (size_t)3072 * 1024 * 2;
  unsigned short* Wpt   = (unsigned short*)ws;  ws += (size_t)1024 * 1024 * 2;
  unsigned short* QKV   = (unsigned short*)ws;  ws += (size_t)3 * 32 * 2048 * 64 * 2;
  unsigned short* Ab    = (unsigned short*)ws;  ws += (size_t)4096 * 1024 * 2;

  unsigned short* Qb = QKV;
  unsigned short* Kb = QKV + (size_t)32 * 2048 * 64;
  unsigned short* Vb = QKV + (size_t)2 * 32 * 2048 * 64;

  cvt_kernel<<<4096, 256, 0, stream>>>(hs, Xb, 4096 * 1024 / 4);
  tpose_kernel<<<(1024 / 32) * (3072 / 32), 256, 0, stream>>>(c_attn_w, Wqkvt, 1024, 3072);
  tpose_kernel<<<(1024 / 32) * (1024 / 32), 256, 0, stream>>>(c_proj_w, Wpt, 1024, 1024);
  gemm_bt<0><<<32 * 24, 256, 0, stream>>>(Xb, Wqkvt, c_attn_b, QKV, 3072);
  attn_kernel<<<32 * 32, 256, 0, stream>>>(Qb, Kb, Vb, Ab);
  gemm_bt<1><<<32 * 8, 256, 0, stream>>>(Ab, Wpt, c_proj_b, d_out, 1024);
}